// Round 16
// baseline (756.530 us; speedup 1.0000x reference)
//
#include <hip/hip_runtime.h>
#include <utility>

typedef unsigned short u16;
typedef __bf16  bf16x8 __attribute__((ext_vector_type(8)));
typedef float   f32x4  __attribute__((ext_vector_type(4)));
typedef unsigned short u16x4 __attribute__((ext_vector_type(4)));

constexpr int Bc = 2, Tc = 1024, Oc = 512, Dc = 1024, Hc = 16, Lc = 4, FFc = 4096;
constexpr int Mc = Bc * Tc;   // 2048 tokens
constexpr int Sq = 3 * Dc;    // fused qkv row stride = 3072

__device__ __forceinline__ u16 f2b(float f) {
    unsigned u = __float_as_uint(f);
    u = (u + 0x7fffu + ((u >> 16) & 1u)) >> 16;
    return (u16)u;
}
__device__ __forceinline__ float gelu_f(float x) {
    return 0.5f * x * (1.0f + erff(x * 0.7071067811865476f));
}

typedef const __attribute__((address_space(1))) void* gas_p;
typedef __attribute__((address_space(3))) void* las_p;
__device__ __forceinline__ void gload16(const void* g, void* l) {
    __builtin_amdgcn_global_load_lds((gas_p)g, (las_p)l, 16, 0, 0);
}

// ---------------- uber weight transpose: all weights in ONE launch ----------
// f32 [R,C] (nz batched) -> bf16 [C,R].  Block = one 64x64 tile, vectorized
// f32x4 reads / u16x4 writes, both NON-TEMPORAL (nt): 321MB streams once and
// must not thrash L2/L3 (r12-r15: 4 codings all pinned ~87us @2.4TB/s;
// remaining hypothesis is cache-allocate pollution).  R%64==0, C%64==0.
struct WTSeg {
    const float* src; u16* dst;
    int R, C, tilesPerZ;
    long inB, outB, cumEnd;
};
struct WTTab { WTSeg e[10]; };

__global__ __launch_bounds__(256) void uber_wtrans(WTTab tab) {
    __shared__ float t[64][65];
    const long id = blockIdx.x;
    int s = 0;
#pragma unroll
    for (int i = 0; i < 10; ++i)
        if (id >= tab.e[i].cumEnd) s = i + 1;
    const WTSeg e = tab.e[s];
    const long start = (s == 0) ? 0 : tab.e[s - 1].cumEnd;
    const long local = id - start;
    const int z = (int)(local / e.tilesPerZ);
    const long tt = local % e.tilesPerZ;
    const int ntx = e.C >> 6;                        // tiles along C (64 wide)
    const int txb = (int)(tt % ntx), tyb = (int)(tt / ntx);
    const float* inp = e.src + (size_t)z * e.inB;
    u16* outp = e.dst + (size_t)z * e.outB;
    const int tid = threadIdx.x;
    const int br = tyb * 64, bc = txb * 64;
    // read 64 rows x 64 f32 (f32x4 nontemporal)
#pragma unroll
    for (int i = 0; i < 4; ++i) {
        const int id2 = i * 256 + tid;
        const int row = id2 >> 4, vc = id2 & 15;
        const f32x4 v = __builtin_nontemporal_load(
            (const f32x4*)(inp + (size_t)(br + row) * e.C + bc + vc * 4));
        *(f32x4*)&t[row][vc * 4] = v;
    }
    __syncthreads();
    // write 64 out-rows (c) x 64 u16 (u16x4 nontemporal)
#pragma unroll
    for (int i = 0; i < 4; ++i) {
        const int id2 = i * 256 + tid;
        const int c = id2 >> 4, vr = id2 & 15;
        u16x4 o;
#pragma unroll
        for (int j = 0; j < 4; ++j) o[j] = f2b(t[vr * 4 + j][c]);
        __builtin_nontemporal_store(o,
            (u16x4*)(outp + (size_t)(bc + c) * e.R + br + vr * 4));
    }
}

// ---------------- bf16 transpose of V slice: qkv[b,:,2048+..] -> vT[b][D][T] --
__global__ __launch_bounds__(256) void btrans(const u16* __restrict__ in,
                                              u16* __restrict__ out, int inStride) {
    __shared__ u16 t[32][33];
    const u16* inp = in + (size_t)blockIdx.z * Tc * inStride;
    u16* outp = out + (size_t)blockIdx.z * Dc * Tc;
    const int tx = threadIdx.x & 31, ty = threadIdx.x >> 5;
    const int br = blockIdx.y * 32, bc = blockIdx.x * 32;   // br: T rows, bc: D cols
#pragma unroll
    for (int i = 0; i < 32; i += 8)
        t[ty + i][tx] = inp[(size_t)(br + ty + i) * inStride + bc + tx];
    __syncthreads();
#pragma unroll
    for (int i = 0; i < 32; i += 8)
        outp[(size_t)(bc + ty + i) * Tc + br + tx] = t[tx][ty + i];
}

// ---------------- f32 -> bf16 convert ----------------
__global__ __launch_bounds__(256) void cvt_bf(const float* __restrict__ in,
                                              u16* __restrict__ out, int n) {
    int i = blockIdx.x * 256 + threadIdx.x;
    if (i * 4 >= n) return;
    float4 v = ((const float4*)in)[i];
    u16x4 r;
    r[0] = f2b(v.x); r[1] = f2b(v.y); r[2] = f2b(v.z); r[3] = f2b(v.w);
    ((u16x4*)out)[i] = r;
}

// ---------------- pack qkv bias [L][3072] ----------------
__global__ __launch_bounds__(256) void pack_qkv_bias(const float* __restrict__ bq,
    const float* __restrict__ bk, const float* __restrict__ bv, float* __restrict__ out) {
    int i = blockIdx.x * 256 + threadIdx.x;       // over L*3072
    int l = i / Sq, j = i % Sq;
    float v = (j < Dc) ? bq[l * Dc + j] : (j < 2 * Dc ? bk[l * Dc + j - Dc] : bv[l * Dc + j - 2 * Dc]);
    out[i] = v;
}

// ---------------- LayerNorm over D=1024 (one block per row) ----------------
__global__ __launch_bounds__(256) void ln_kernel(
    const float* __restrict__ in, const float* __restrict__ gam,
    const float* __restrict__ bet, const float* __restrict__ pos,
    float* __restrict__ outf, u16* __restrict__ outb, int do_gelu) {
    const int row = blockIdx.x, tid = threadIdx.x;
    const float4 v = ((const float4*)(in + (size_t)row * Dc))[tid];
    float s  = v.x + v.y + v.z + v.w;
    float ss = v.x * v.x + v.y * v.y + v.z * v.z + v.w * v.w;
#pragma unroll
    for (int m = 1; m < 64; m <<= 1) {
        s  += __shfl_xor(s,  m, 64);
        ss += __shfl_xor(ss, m, 64);
    }
    __shared__ float red[8];
    const int w = tid >> 6;
    if ((tid & 63) == 0) { red[w] = s; red[4 + w] = ss; }
    __syncthreads();
    s  = red[0] + red[1] + red[2] + red[3];
    ss = red[4] + red[5] + red[6] + red[7];
    const float mean = s * (1.0f / Dc);
    const float rstd = rsqrtf(ss * (1.0f / Dc) - mean * mean + 1e-5f);
    const float4 gv = ((const float4*)gam)[tid];
    const float4 bv = ((const float4*)bet)[tid];
    float y0 = (v.x - mean) * rstd * gv.x + bv.x;
    float y1 = (v.y - mean) * rstd * gv.y + bv.y;
    float y2 = (v.z - mean) * rstd * gv.z + bv.z;
    float y3 = (v.w - mean) * rstd * gv.w + bv.w;
    if (do_gelu) { y0 = gelu_f(y0); y1 = gelu_f(y1); y2 = gelu_f(y2); y3 = gelu_f(y3); }
    if (pos) {
        const float4 pv = ((const float4*)(pos + (size_t)(row & (Tc - 1)) * Dc))[tid];
        y0 += pv.x; y1 += pv.y; y2 += pv.z; y3 += pv.w;
    }
    if (outf) {
        float4 o; o.x = y0; o.y = y1; o.z = y2; o.w = y3;
        ((float4*)(outf + (size_t)row * Dc))[tid] = o;
    }
    if (outb) {
        u16x4 r; r[0] = f2b(y0); r[1] = f2b(y1); r[2] = f2b(y2); r[3] = f2b(y3);
        ((u16x4*)(outb + (size_t)row * Dc))[tid] = r;
    }
}

// -------- fused: xf = sum(NP planes)+bias+resid ; then LN(xf) ---------------
template<int NP>
__global__ __launch_bounds__(256) void red2_ln(
    const float* __restrict__ p, const float* __restrict__ bias,
    const float* __restrict__ resid, float* __restrict__ xfout,
    const float* __restrict__ gam, const float* __restrict__ bet,
    float* __restrict__ lnoutf, u16* __restrict__ lnoutb) {
    const int row = blockIdx.x, tid = threadIdx.x;
    const f32x4 bb = ((const f32x4*)bias)[tid];
    const f32x4 r  = ((const f32x4*)(resid + (size_t)row * Dc))[tid];
    f32x4 v;
#pragma unroll
    for (int j = 0; j < 4; ++j) v[j] = bb[j] + r[j];
#pragma unroll
    for (int pl = 0; pl < NP; ++pl) {
        const f32x4 a = ((const f32x4*)(p + (size_t)pl * Mc * Dc + (size_t)row * Dc))[tid];
#pragma unroll
        for (int j = 0; j < 4; ++j) v[j] += a[j];
    }
    ((f32x4*)(xfout + (size_t)row * Dc))[tid] = v;
    float s  = v[0] + v[1] + v[2] + v[3];
    float ss = v[0]*v[0] + v[1]*v[1] + v[2]*v[2] + v[3]*v[3];
#pragma unroll
    for (int m = 1; m < 64; m <<= 1) {
        s  += __shfl_xor(s,  m, 64);
        ss += __shfl_xor(ss, m, 64);
    }
    __shared__ float red[8];
    const int w = tid >> 6;
    if ((tid & 63) == 0) { red[w] = s; red[4 + w] = ss; }
    __syncthreads();
    s  = red[0] + red[1] + red[2] + red[3];
    ss = red[4] + red[5] + red[6] + red[7];
    const float mean = s * (1.0f / Dc);
    const float rstd = rsqrtf(ss * (1.0f / Dc) - mean * mean + 1e-5f);
    const f32x4 gv = ((const f32x4*)gam)[tid];
    const f32x4 bv = ((const f32x4*)bet)[tid];
    f32x4 y;
#pragma unroll
    for (int j = 0; j < 4; ++j) y[j] = (v[j] - mean) * rstd * gv[j] + bv[j];
    if (lnoutf) ((f32x4*)(lnoutf + (size_t)row * Dc))[tid] = y;
    u16x4 o;
#pragma unroll
    for (int j = 0; j < 4; ++j) o[j] = f2b(y[j]);
    ((u16x4*)(lnoutb + (size_t)row * Dc))[tid] = o;
}

// ============ shared GEMM helpers ==========================================
// 8x8 super-tile XCD swizzle: requires gx%8==0 && nwg%64==0.
__device__ __forceinline__ void xcd_map(int& bx, int& by) {
    const int gx = gridDim.x;
    const int nwg = gx * gridDim.y;
    const int orig = blockIdx.y * gx + blockIdx.x;
    const int wgid = (orig & 7) * (nwg >> 3) + (orig >> 3);
    const int s = wgid >> 6, q = wgid & 63;
    const int nsx = gx >> 3;
    const int sy = s / nsx, sx = s - sy * nsx;
    by = sy * 8 + (q >> 3);
    bx = sx * 8 + (q & 7);
}

// ---------------- gemm_s: SINGLE-buffered m97-style loop (replay-proven) ----
// stage-DMA -> vmcnt(0)+barrier -> compute -> barrier.
template<int BM, int BN, int FM, int FN, int WM, int WN, int OCC>
__global__ __launch_bounds__(256, OCC) void gemm_s(
    const u16* __restrict__ A, const u16* __restrict__ Bt,
    const float* __restrict__ bias, const float* resid,
    float* Cf, u16* Cb, int M, int N, int Kst, int Kl, int do_gelu) {
    __shared__ u16 sA[BM][64];
    __shared__ u16 sB[BN][64];
    constexpr int NA = BM / 32;
    constexpr int NB = BN / 32;
    const int tid = threadIdx.x;
    const int lane = tid & 63, w = tid >> 6;
    const int lr = lane & 15, g = lane >> 4;
    const int wm = w / WN, wn = w % WN;

    A  += (size_t)blockIdx.z * Kl;
    Bt += (size_t)blockIdx.z * Kl;
    Cf += (size_t)blockIdx.z * M * N;

    int bx, by;
    xcd_map(bx, by);
    const long m0 = (long)by * BM, n0 = (long)bx * BN;

    const f32x4 fzero = {0.f, 0.f, 0.f, 0.f};
    f32x4 acc[FM][FN];
#pragma unroll
    for (int i = 0; i < FM; ++i)
#pragma unroll
        for (int j = 0; j < FN; ++j) acc[i][j] = fzero;

    const int nt = Kl / 64;
    const int srow = lane >> 3, scc = lane & 7;
    const u16* pa[NA];
    const u16* pb[NB];
#pragma unroll
    for (int r = 0; r < NA; ++r)
        pa[r] = A + (size_t)(m0 + r * 32 + w * 8 + srow) * Kst + ((scc ^ srow) * 8);
#pragma unroll
    for (int r = 0; r < NB; ++r)
        pb[r] = Bt + (size_t)(n0 + r * 32 + w * 8 + srow) * Kst + ((scc ^ srow) * 8);

    for (int t = 0; t < nt; ++t) {
#pragma unroll
        for (int r = 0; r < NA; ++r) { gload16(pa[r], &sA[r * 32 + w * 8][0]); pa[r] += 64; }
#pragma unroll
        for (int r = 0; r < NB; ++r) { gload16(pb[r], &sB[r * 32 + w * 8][0]); pb[r] += 64; }
        asm volatile("s_waitcnt vmcnt(0)" ::: "memory");
        __builtin_amdgcn_sched_barrier(0);
        __syncthreads();
#pragma unroll
        for (int ks = 0; ks < 2; ++ks) {
            bf16x8 fa[FM], fb[FN];
#pragma unroll
            for (int mi = 0; mi < FM; ++mi) {
                int row = wm * (16 * FM) + mi * 16 + lr;
                fa[mi] = *(const bf16x8*)&sA[row][((ks * 4 + g) ^ (row & 7)) * 8];
            }
#pragma unroll
            for (int ni = 0; ni < FN; ++ni) {
                int row = wn * (16 * FN) + ni * 16 + lr;
                fb[ni] = *(const bf16x8*)&sB[row][((ks * 4 + g) ^ (row & 7)) * 8];
            }
#pragma unroll
            for (int mi = 0; mi < FM; ++mi)
#pragma unroll
                for (int ni = 0; ni < FN; ++ni)
                    acc[mi][ni] = __builtin_amdgcn_mfma_f32_16x16x32_bf16(
                        fa[mi], fb[ni], acc[mi][ni], 0, 0, 0);
        }
        __syncthreads();
    }
#pragma unroll
    for (int mi = 0; mi < FM; ++mi) {
#pragma unroll
        for (int ni = 0; ni < FN; ++ni) {
            const long nc = n0 + wn * (16 * FN) + ni * 16 + lr;
            const float bvv = bias ? bias[nc] : 0.0f;
#pragma unroll
            for (int j = 0; j < 4; ++j) {
                const long mr = m0 + wm * (16 * FM) + mi * 16 + g * 4 + j;
                float v = acc[mi][ni][j] + bvv;
                if (resid) v += resid[(size_t)mr * N + nc];
                if (do_gelu) v = gelu_f(v);
                if (Cf) Cf[(size_t)mr * N + nc] = v;
                if (Cb) Cb[(size_t)mr * N + nc] = f2b(v);
            }
        }
    }
}

// ---------------- causal flash attention -----------------------------------
// K/V double-buffered in LDS with register prefetch (1 barrier/iter);
// long-first qc order (reversed) hides causal-triangle tail.
__global__ __launch_bounds__(256, 2) void attn_kernel(
    const u16* __restrict__ qkv, const u16* __restrict__ Vt, u16* __restrict__ Yg) {
    __shared__ u16 sK[2][64][64];
    __shared__ u16 sV[2][64][64];
    __shared__ u16 sP[4][16][64];
    const int tid = threadIdx.x, w = tid >> 6, lane = tid & 63;
    const int lr = lane & 15, g = lane >> 4;
    const int hw = blockIdx.x;
    const int xcd = hw & 7, slot = hw >> 3;        // slot 0..63
    const int bh = xcd + 8 * (slot >> 4);          // 0..31
    const int qc = 15 - (slot & 15);               // 64-row chunk, LONG FIRST
    const int h = bh & 15, b = bh >> 4;
    const int tq0 = qc * 64 + w * 16;
    const u16* Qp = qkv + (size_t)b * Tc * Sq + h * 64;
    const u16* Kp = qkv + (size_t)b * Tc * Sq + Dc + h * 64;
    const u16* Vp = Vt + ((size_t)b * Dc + h * 64) * Tc;

    bf16x8 qf[2];
#pragma unroll
    for (int ks = 0; ks < 2; ++ks)
        qf[ks] = *(const bf16x8*)(Qp + (size_t)(tq0 + lr) * Sq + ks * 32 + g * 8);

    const f32x4 fzero = {0.f, 0.f, 0.f, 0.f};
    f32x4 o[4];
    float mst[4], lst[4];
#pragma unroll
    for (int j = 0; j < 4; ++j) { mst[j] = -1e30f; lst[j] = 0.f; }
#pragma unroll
    for (int ni = 0; ni < 4; ++ni) o[ni] = fzero;

    const int c0 = tid, c1 = tid + 256;
    const int row0 = c0 >> 3, cc0 = c0 & 7;
    const int row1 = c1 >> 3, cc1 = c1 & 7;
    bf16x8 kr[2], vr[2];
    auto kvload = [&](int jk) {
        kr[0] = *(const bf16x8*)(Kp + (size_t)(jk * 64 + row0) * Sq + cc0 * 8);
        kr[1] = *(const bf16x8*)(Kp + (size_t)(jk * 64 + row1) * Sq + cc1 * 8);
        vr[0] = *(const bf16x8*)(Vp + (size_t)row0 * Tc + jk * 64 + cc0 * 8);
        vr[1] = *(const bf16x8*)(Vp + (size_t)row1 * Tc + jk * 64 + cc1 * 8);
    };
    auto kvwrite = [&](int buf) {
        *(bf16x8*)&sK[buf][row0][(cc0 ^ (row0 & 7)) * 8] = kr[0];
        *(bf16x8*)&sK[buf][row1][(cc1 ^ (row1 & 7)) * 8] = kr[1];
        *(bf16x8*)&sV[buf][row0][(cc0 ^ (row0 & 7)) * 8] = vr[0];
        *(bf16x8*)&sV[buf][row1][(cc1 ^ (row1 & 7)) * 8] = vr[1];
    };

    kvload(0);
    kvwrite(0);
    __syncthreads();
    for (int jk = 0; jk <= qc; ++jk) {
        const int cur = jk & 1;
        if (jk < qc) kvload(jk + 1);
        // QK^T
        f32x4 s[4];
#pragma unroll
        for (int ni = 0; ni < 4; ++ni) {
            const int row = ni * 16 + lr;
            bf16x8 kf0 = *(const bf16x8*)&sK[cur][row][((0 + g) ^ (lr & 7)) * 8];
            bf16x8 kf1 = *(const bf16x8*)&sK[cur][row][((4 + g) ^ (lr & 7)) * 8];
            s[ni] = __builtin_amdgcn_mfma_f32_16x16x32_bf16(qf[0], kf0, fzero, 0, 0, 0);
            s[ni] = __builtin_amdgcn_mfma_f32_16x16x32_bf16(qf[1], kf1, s[ni], 0, 0, 0);
        }
#pragma unroll
        for (int ni = 0; ni < 4; ++ni)
#pragma unroll
            for (int j = 0; j < 4; ++j) {
                float v = s[ni][j] * 0.125f;
                int tk = jk * 64 + ni * 16 + lr;
                int tq = tq0 + g * 4 + j;
                if (tk > tq) v = -1e30f;
                s[ni][j] = v;
            }
        float fs[4];
#pragma unroll
        for (int j = 0; j < 4; ++j) {
            float pm = fmaxf(fmaxf(s[0][j], s[1][j]), fmaxf(s[2][j], s[3][j]));
            pm = fmaxf(pm, __shfl_xor(pm, 1, 16));
            pm = fmaxf(pm, __shfl_xor(pm, 2, 16));
            pm = fmaxf(pm, __shfl_xor(pm, 4, 16));
            pm = fmaxf(pm, __shfl_xor(pm, 8, 16));
            const float m2 = fmaxf(mst[j], pm);
            fs[j] = __expf(mst[j] - m2);
#pragma unroll
            for (int ni = 0; ni < 4; ++ni)
                s[ni][j] = __expf(s[ni][j] - m2);
            float rsum = s[0][j] + s[1][j] + s[2][j] + s[3][j];
            rsum += __shfl_xor(rsum, 1, 16);
            rsum += __shfl_xor(rsum, 2, 16);
            rsum += __shfl_xor(rsum, 4, 16);
            rsum += __shfl_xor(rsum, 8, 16);
            lst[j] = lst[j] * fs[j] + rsum;
            mst[j] = m2;
        }
#pragma unroll
        for (int ni = 0; ni < 4; ++ni)
#pragma unroll
            for (int j = 0; j < 4; ++j) o[ni][j] *= fs[j];
#pragma unroll
        for (int ni = 0; ni < 4; ++ni)
#pragma unroll
            for (int j = 0; j < 4; ++j) {
                int row = g * 4 + j;
                int col = ni * 16 + lr;
                sP[w][row][(((col >> 3) ^ (row & 7)) << 3) | (col & 7)] = f2b(s[ni][j]);
            }
#pragma unroll
        for (int ks = 0; ks < 2; ++ks) {
            bf16x8 pf = *(const bf16x8*)&sP[w][lr][((ks * 4 + g) ^ (lr & 7)) * 8];
#pragma unroll
            for (int ni = 0; ni < 4; ++ni) {
                const int row = ni * 16 + lr;
                bf16x8 vf = *(const bf16x8*)&sV[cur][row][((ks * 4 + g) ^ (lr & 7)) * 8];
                o[ni] = __builtin_amdgcn_mfma_f32_16x16x32_bf16(pf, vf, o[ni], 0, 0, 0);
            }
        }
        if (jk < qc) kvwrite(cur ^ 1);
        __syncthreads();
    }
#pragma unroll
    for (int ni = 0; ni < 4; ++ni)
#pragma unroll
        for (int j = 0; j < 4; ++j) {
            int tq = tq0 + g * 4 + j;
            int col = h * 64 + ni * 16 + lr;
            Yg[(size_t)(b * Tc + tq) * Dc + col] = f2b(o[ni][j] / lst[j]);
        }
}

// ---------------------------------------------------------------------------
extern "C" void kernel_launch(void* const* d_in, const int* in_sizes, int n_in,
                              void* d_out, int out_size, void* d_ws, size_t ws_size,
                              hipStream_t stream) {
    const float* obs    = (const float*)d_in[0];
    const float* enc_w1 = (const float*)d_in[1];
    const float* enc_b1 = (const float*)d_in[2];
    const float* enc_g1 = (const float*)d_in[3];
    const float* enc_be1= (const float*)d_in[4];
    const float* enc_w2 = (const float*)d_in[5];
    const float* enc_b2 = (const float*)d_in[6];
    const float* enc_w3 = (const float*)d_in[7];
    const float* enc_b3 = (const float*)d_in[8];
    const float* enc_g2 = (const float*)d_in[9];
    const float* enc_be2= (const float*)d_in[10];
    const float* pos_emb= (const float*)d_in[11];
    const float* ln1_g  = (const float*)d_in[12];
    const float* ln1_b  = (const float*)d_in[13];
    const float* wq     = (const float*)d_in[14];
    const float* bq     = (const float*)d_in[15];
    const float* wk     = (const float*)d_in[16];
    const float* bk     = (const float*)d_in[17];
    const float* wv     = (const float*)d_in[18];
    const float* bv     = (const float*)d_in[19];
    const float* wo     = (const float*)d_in[20];
    const float* bo     = (const float*)d_in[21];
    const float* ln2_g  = (const float*)d_in[22];
    const float* ln2_b  = (const float*)d_in[23];
    const float* mlp_w1 = (const float*)d_in[24];
    const float* mlp_b1 = (const float*)d_in[25];
    const float* mlp_w2 = (const float*)d_in[26];
    const float* mlp_b2 = (const float*)d_in[27];
    const float* lnf_g  = (const float*)d_in[28];
    const float* lnf_b  = (const float*)d_in[29];
    const float* dec_w  = (const float*)d_in[30];
    const float* dec_b  = (const float*)d_in[31];

    float* out_x = (float*)d_out;
    float* out_o = out_x + (size_t)Mc * Dc;

    char* base = (char*)d_ws;
    size_t off = 0;
    auto ab = [&](size_t e) -> u16* {
        u16* r = (u16*)(base + off); off += (e * 2 + 255) & ~(size_t)255; return r; };
    auto af = [&](size_t e) -> float* {
        float* r = (float*)(base + off); off += (e * 4 + 255) & ~(size_t)255; return r; };

    u16* wt_e1   = ab((size_t)Dc * Oc);
    u16* wt_e2   = ab((size_t)Dc * Dc);
    u16* wt_e3   = ab((size_t)Dc * Dc);
    u16* wtqkv   = ab((size_t)Lc * 3 * Dc * Dc);
    u16* wto     = ab((size_t)Lc * Dc * Dc);
    u16* wtm1    = ab((size_t)Lc * Dc * FFc);
    u16* wtm2    = ab((size_t)Lc * FFc * Dc);
    u16* wt_d    = ab((size_t)Oc * Dc);
    float* qkvb  = af((size_t)Lc * Sq);

    u16*   obs_bf = ab((size_t)Mc * Oc);
    float* tmpf   = af((size_t)Mc * Dc);
    float* xf     = af((size_t)Mc * Dc);
    float* x2f    = af((size_t)Mc * Dc);
    u16*   hn_bf  = ab((size_t)Mc * Dc);
    u16*   qkv    = ab((size_t)Mc * Sq);
    u16*   vT     = ab((size_t)Mc * Dc);
    u16*   y_bf   = ab((size_t)Mc * Dc);
    u16*   ff_bf  = ab((size_t)Mc * FFc);
    float* pk     = af((size_t)4 * Mc * Dc);   // split-K partials (4 planes)

    // ---- uber weight prep: ONE launch for all transposes (64x64, nt) ----
    WTTab tab;
    long cum = 0;
    auto seg = [&](int i, const float* src, u16* dst, int R, int C, int nz,
                   long inB, long outB) {
        int tpz = (R / 64) * (C / 64);
        cum += (long)tpz * nz;
        tab.e[i] = WTSeg{src, dst, R, C, tpz, inB, outB, cum};
    };
    seg(0, enc_w1, wt_e1, Oc, Dc, 1, 0, 0);
    seg(1, enc_w2, wt_e2, Dc, Dc, 1, 0, 0);
    seg(2, enc_w3, wt_e3, Dc, Dc, 1, 0, 0);
    seg(3, wq, wtqkv,              Dc, Dc, Lc, (long)Dc * Dc, (long)3 * Dc * Dc);
    seg(4, wk, wtqkv + Dc * Dc,    Dc, Dc, Lc, (long)Dc * Dc, (long)3 * Dc * Dc);
    seg(5, wv, wtqkv + 2 * Dc * Dc,Dc, Dc, Lc, (long)Dc * Dc, (long)3 * Dc * Dc);
    seg(6, wo, wto, Dc, Dc, Lc, (long)Dc * Dc, (long)Dc * Dc);
    seg(7, mlp_w1, wtm1, Dc, FFc, Lc, (long)Dc * FFc, (long)Dc * FFc);
    seg(8, mlp_w2, wtm2, FFc, Dc, Lc, (long)Dc * FFc, (long)Dc * FFc);
    seg(9, dec_w, wt_d, Dc, Oc, 1, 0, 0);
    uber_wtrans<<<dim3((unsigned)cum), 256, 0, stream>>>(tab);
    pack_qkv_bias<<<dim3(Lc * Sq / 256), 256, 0, stream>>>(bq, bk, bv, qkvb);
    cvt_bf<<<dim3((Mc * Oc / 4 + 255) / 256), 256, 0, stream>>>(obs, obs_bf, Mc * Oc);

    // big-N GEMMs: 128x64 tile, 4 blocks/CU;  small GEMMs: 64x64 tile
    auto gS = [&](const u16* A, const u16* Bt, const float* bias, const float* resid,
                  float* Cf, u16* Cb, int M, int N, int K, int gel) {
        gemm_s<128, 64, 4, 2, 2, 2, 4><<<dim3(N / 64, M / 128), 256, 0, stream>>>(
            A, Bt, bias, resid, Cf, Cb, M, N, K, K, gel);
    };
    auto g64 = [&](const u16* A, const u16* Bt, const float* bias, const float* resid,
                   float* Cf, u16* Cb, int M, int N, int K, int gel) {
        gemm_s<64, 64, 2, 2, 2, 2, 4><<<dim3(N / 64, M / 64), 256, 0, stream>>>(
            A, Bt, bias, resid, Cf, Cb, M, N, K, K, gel);
    };
    auto lnk = [&](const float* in, const float* gg, const float* bb, const float* pos,
                   float* outf, u16* outb, int gel) {
        ln_kernel<<<dim3(Mc), 256, 0, stream>>>(in, gg, bb, pos, outf, outb, gel);
    };

    // encoder MLP
    g64(obs_bf, wt_e1, enc_b1, nullptr, tmpf, nullptr, Mc, Dc, Oc, 0);
    lnk(tmpf, enc_g1, enc_be1, nullptr, nullptr, hn_bf, 1);
    g64(hn_bf, wt_e2, enc_b2, nullptr, nullptr, y_bf, Mc, Dc, Dc, 1);
    g64(y_bf, wt_e3, enc_b3, nullptr, tmpf, nullptr, Mc, Dc, Dc, 0);
    lnk(tmpf, enc_g2, enc_be2, pos_emb, xf, nullptr, 0);

    // ln1 of layer 0
    lnk(xf, ln1_g, ln1_b, nullptr, nullptr, hn_bf, 0);

    // transformer blocks
    for (int l = 0; l < Lc; ++l) {
        gS(hn_bf, wtqkv + (size_t)l * 3 * Dc * Dc, qkvb + (size_t)l * Sq, nullptr,
           nullptr, qkv, Mc, Sq, Dc, 0);
        btrans<<<dim3(Dc / 32, Tc / 32, Bc), 256, 0, stream>>>(qkv + 2 * Dc, vT, Sq);
        attn_kernel<<<dim3(Bc * Hc * (Tc / 64)), 256, 0, stream>>>(qkv, vT, y_bf);
        // wo projection: split-K=2 -> fp32 partials, 1024 blocks (4/CU)
        gemm_s<64, 64, 2, 2, 2, 2, 4><<<dim3(Dc / 64, Mc / 64, 2), 256, 0, stream>>>(
            y_bf, wto + (size_t)l * Dc * Dc, nullptr, nullptr, pk, nullptr,
            Mc, Dc, Dc, Dc / 2, 0);
        // fused: x2f = p0+p1+bo+xf ; ln2 -> hn_bf
        red2_ln<2><<<dim3(Mc), 256, 0, stream>>>(
            pk, bo + (size_t)l * Dc, xf, x2f,
            ln2_g + (size_t)l * Dc, ln2_b + (size_t)l * Dc, nullptr, hn_bf);
        gS(hn_bf, wtm1 + (size_t)l * Dc * FFc, mlp_b1 + (size_t)l * FFc, nullptr,
           nullptr, ff_bf, Mc, FFc, Dc, 1);
        // mlp2: split-K=4 -> fp32 partials (128x64 tile, 1024 blocks -> 4/CU)
        gemm_s<128, 64, 4, 2, 2, 2, 4><<<dim3(Dc / 64, Mc / 128, 4), 256, 0, stream>>>(
            ff_bf, wtm2 + (size_t)l * FFc * Dc, nullptr, nullptr, pk, nullptr,
            Mc, Dc, FFc, FFc / 4, 0);
        // fused reduce(+bias+resid) -> xf, then LN (ln1[l+1] or lnf)
        if (l < Lc - 1) {
            red2_ln<4><<<dim3(Mc), 256, 0, stream>>>(
                pk, mlp_b2 + (size_t)l * Dc, x2f, xf,
                ln1_g + (size_t)(l + 1) * Dc, ln1_b + (size_t)(l + 1) * Dc,
                nullptr, hn_bf);
        } else {
            red2_ln<4><<<dim3(Mc), 256, 0, stream>>>(
                pk, mlp_b2 + (size_t)l * Dc, x2f, xf,
                lnf_g, lnf_b, out_x, hn_bf);
        }
    }

    // decoder
    g64(hn_bf, wt_d, dec_b, nullptr, out_o, nullptr, Mc, Oc, Dc, 0);
}

// Round 17
// 684.841 us; speedup vs baseline: 1.1047x; 1.1047x over previous
//
#include <hip/hip_runtime.h>
#include <utility>

typedef unsigned short u16;
typedef __bf16  bf16x8 __attribute__((ext_vector_type(8)));
typedef float   f32x4  __attribute__((ext_vector_type(4)));
typedef unsigned short u16x4 __attribute__((ext_vector_type(4)));

constexpr int Bc = 2, Tc = 1024, Oc = 512, Dc = 1024, Hc = 16, Lc = 4, FFc = 4096;
constexpr int Mc = Bc * Tc;   // 2048 tokens
constexpr int Sq = 3 * Dc;    // fused qkv row stride = 3072

__device__ __forceinline__ u16 f2b(float f) {
    unsigned u = __float_as_uint(f);
    u = (u + 0x7fffu + ((u >> 16) & 1u)) >> 16;
    return (u16)u;
}
__device__ __forceinline__ float gelu_f(float x) {
    return 0.5f * x * (1.0f + erff(x * 0.7071067811865476f));
}

typedef const __attribute__((address_space(1))) void* gas_p;
typedef __attribute__((address_space(3))) void* las_p;
__device__ __forceinline__ void gload16(const void* g, void* l) {
    __builtin_amdgcn_global_load_lds((gas_p)g, (las_p)l, 16, 0, 0);
}

// ---------------- uber weight transpose: all weights in ONE launch ----------
// f32 [R,C] (nz batched) -> bf16 [C,R].  Block = one 64x64 tile, vectorized
// f32x4 NT reads (source read once - keep out of L3; r16: 87->60us) but
// REGULAR u16x4 stores (bf16 weights are re-read by the GEMMs and must stay
// L2/L3-resident; r16's NT stores cost ~60us across downstream GEMMs).
struct WTSeg {
    const float* src; u16* dst;
    int R, C, tilesPerZ;
    long inB, outB, cumEnd;
};
struct WTTab { WTSeg e[10]; };

__global__ __launch_bounds__(256) void uber_wtrans(WTTab tab) {
    __shared__ float t[64][65];
    const long id = blockIdx.x;
    int s = 0;
#pragma unroll
    for (int i = 0; i < 10; ++i)
        if (id >= tab.e[i].cumEnd) s = i + 1;
    const WTSeg e = tab.e[s];
    const long start = (s == 0) ? 0 : tab.e[s - 1].cumEnd;
    const long local = id - start;
    const int z = (int)(local / e.tilesPerZ);
    const long tt = local % e.tilesPerZ;
    const int ntx = e.C >> 6;                        // tiles along C (64 wide)
    const int txb = (int)(tt % ntx), tyb = (int)(tt / ntx);
    const float* inp = e.src + (size_t)z * e.inB;
    u16* outp = e.dst + (size_t)z * e.outB;
    const int tid = threadIdx.x;
    const int br = tyb * 64, bc = txb * 64;
    // read 64 rows x 64 f32 (f32x4 nontemporal - single-use stream)
#pragma unroll
    for (int i = 0; i < 4; ++i) {
        const int id2 = i * 256 + tid;
        const int row = id2 >> 4, vc = id2 & 15;
        const f32x4 v = __builtin_nontemporal_load(
            (const f32x4*)(inp + (size_t)(br + row) * e.C + bc + vc * 4));
        *(f32x4*)&t[row][vc * 4] = v;
    }
    __syncthreads();
    // write 64 out-rows (c) x 64 u16 (u16x4 REGULAR - GEMMs re-read these)
#pragma unroll
    for (int i = 0; i < 4; ++i) {
        const int id2 = i * 256 + tid;
        const int c = id2 >> 4, vr = id2 & 15;
        u16x4 o;
#pragma unroll
        for (int j = 0; j < 4; ++j) o[j] = f2b(t[vr * 4 + j][c]);
        *(u16x4*)(outp + (size_t)(bc + c) * e.R + br + vr * 4) = o;
    }
}

// ---------------- bf16 transpose of V slice: qkv[b,:,2048+..] -> vT[b][D][T] --
__global__ __launch_bounds__(256) void btrans(const u16* __restrict__ in,
                                              u16* __restrict__ out, int inStride) {
    __shared__ u16 t[32][33];
    const u16* inp = in + (size_t)blockIdx.z * Tc * inStride;
    u16* outp = out + (size_t)blockIdx.z * Dc * Tc;
    const int tx = threadIdx.x & 31, ty = threadIdx.x >> 5;
    const int br = blockIdx.y * 32, bc = blockIdx.x * 32;   // br: T rows, bc: D cols
#pragma unroll
    for (int i = 0; i < 32; i += 8)
        t[ty + i][tx] = inp[(size_t)(br + ty + i) * inStride + bc + tx];
    __syncthreads();
#pragma unroll
    for (int i = 0; i < 32; i += 8)
        outp[(size_t)(bc + ty + i) * Tc + br + tx] = t[tx][ty + i];
}

// ---------------- f32 -> bf16 convert ----------------
__global__ __launch_bounds__(256) void cvt_bf(const float* __restrict__ in,
                                              u16* __restrict__ out, int n) {
    int i = blockIdx.x * 256 + threadIdx.x;
    if (i * 4 >= n) return;
    float4 v = ((const float4*)in)[i];
    u16x4 r;
    r[0] = f2b(v.x); r[1] = f2b(v.y); r[2] = f2b(v.z); r[3] = f2b(v.w);
    ((u16x4*)out)[i] = r;
}

// ---------------- pack qkv bias [L][3072] ----------------
__global__ __launch_bounds__(256) void pack_qkv_bias(const float* __restrict__ bq,
    const float* __restrict__ bk, const float* __restrict__ bv, float* __restrict__ out) {
    int i = blockIdx.x * 256 + threadIdx.x;       // over L*3072
    int l = i / Sq, j = i % Sq;
    float v = (j < Dc) ? bq[l * Dc + j] : (j < 2 * Dc ? bk[l * Dc + j - Dc] : bv[l * Dc + j - 2 * Dc]);
    out[i] = v;
}

// ---------------- LayerNorm over D=1024 (one block per row) ----------------
__global__ __launch_bounds__(256) void ln_kernel(
    const float* __restrict__ in, const float* __restrict__ gam,
    const float* __restrict__ bet, const float* __restrict__ pos,
    float* __restrict__ outf, u16* __restrict__ outb, int do_gelu) {
    const int row = blockIdx.x, tid = threadIdx.x;
    const float4 v = ((const float4*)(in + (size_t)row * Dc))[tid];
    float s  = v.x + v.y + v.z + v.w;
    float ss = v.x * v.x + v.y * v.y + v.z * v.z + v.w * v.w;
#pragma unroll
    for (int m = 1; m < 64; m <<= 1) {
        s  += __shfl_xor(s,  m, 64);
        ss += __shfl_xor(ss, m, 64);
    }
    __shared__ float red[8];
    const int w = tid >> 6;
    if ((tid & 63) == 0) { red[w] = s; red[4 + w] = ss; }
    __syncthreads();
    s  = red[0] + red[1] + red[2] + red[3];
    ss = red[4] + red[5] + red[6] + red[7];
    const float mean = s * (1.0f / Dc);
    const float rstd = rsqrtf(ss * (1.0f / Dc) - mean * mean + 1e-5f);
    const float4 gv = ((const float4*)gam)[tid];
    const float4 bv = ((const float4*)bet)[tid];
    float y0 = (v.x - mean) * rstd * gv.x + bv.x;
    float y1 = (v.y - mean) * rstd * gv.y + bv.y;
    float y2 = (v.z - mean) * rstd * gv.z + bv.z;
    float y3 = (v.w - mean) * rstd * gv.w + bv.w;
    if (do_gelu) { y0 = gelu_f(y0); y1 = gelu_f(y1); y2 = gelu_f(y2); y3 = gelu_f(y3); }
    if (pos) {
        const float4 pv = ((const float4*)(pos + (size_t)(row & (Tc - 1)) * Dc))[tid];
        y0 += pv.x; y1 += pv.y; y2 += pv.z; y3 += pv.w;
    }
    if (outf) {
        float4 o; o.x = y0; o.y = y1; o.z = y2; o.w = y3;
        ((float4*)(outf + (size_t)row * Dc))[tid] = o;
    }
    if (outb) {
        u16x4 r; r[0] = f2b(y0); r[1] = f2b(y1); r[2] = f2b(y2); r[3] = f2b(y3);
        ((u16x4*)(outb + (size_t)row * Dc))[tid] = r;
    }
}

// -------- fused: xf = sum(NP planes)+bias+resid ; then LN(xf) ---------------
template<int NP>
__global__ __launch_bounds__(256) void red2_ln(
    const float* __restrict__ p, const float* __restrict__ bias,
    const float* __restrict__ resid, float* __restrict__ xfout,
    const float* __restrict__ gam, const float* __restrict__ bet,
    float* __restrict__ lnoutf, u16* __restrict__ lnoutb) {
    const int row = blockIdx.x, tid = threadIdx.x;
    const f32x4 bb = ((const f32x4*)bias)[tid];
    const f32x4 r  = ((const f32x4*)(resid + (size_t)row * Dc))[tid];
    f32x4 v;
#pragma unroll
    for (int j = 0; j < 4; ++j) v[j] = bb[j] + r[j];
#pragma unroll
    for (int pl = 0; pl < NP; ++pl) {
        const f32x4 a = ((const f32x4*)(p + (size_t)pl * Mc * Dc + (size_t)row * Dc))[tid];
#pragma unroll
        for (int j = 0; j < 4; ++j) v[j] += a[j];
    }
    ((f32x4*)(xfout + (size_t)row * Dc))[tid] = v;
    float s  = v[0] + v[1] + v[2] + v[3];
    float ss = v[0]*v[0] + v[1]*v[1] + v[2]*v[2] + v[3]*v[3];
#pragma unroll
    for (int m = 1; m < 64; m <<= 1) {
        s  += __shfl_xor(s,  m, 64);
        ss += __shfl_xor(ss, m, 64);
    }
    __shared__ float red[8];
    const int w = tid >> 6;
    if ((tid & 63) == 0) { red[w] = s; red[4 + w] = ss; }
    __syncthreads();
    s  = red[0] + red[1] + red[2] + red[3];
    ss = red[4] + red[5] + red[6] + red[7];
    const float mean = s * (1.0f / Dc);
    const float rstd = rsqrtf(ss * (1.0f / Dc) - mean * mean + 1e-5f);
    const f32x4 gv = ((const f32x4*)gam)[tid];
    const f32x4 bv = ((const f32x4*)bet)[tid];
    f32x4 y;
#pragma unroll
    for (int j = 0; j < 4; ++j) y[j] = (v[j] - mean) * rstd * gv[j] + bv[j];
    if (lnoutf) ((f32x4*)(lnoutf + (size_t)row * Dc))[tid] = y;
    u16x4 o;
#pragma unroll
    for (int j = 0; j < 4; ++j) o[j] = f2b(y[j]);
    ((u16x4*)(lnoutb + (size_t)row * Dc))[tid] = o;
}

// ============ shared GEMM helpers ==========================================
// 8x8 super-tile XCD swizzle: requires gx%8==0 && nwg%64==0.
__device__ __forceinline__ void xcd_map(int& bx, int& by) {
    const int gx = gridDim.x;
    const int nwg = gx * gridDim.y;
    const int orig = blockIdx.y * gx + blockIdx.x;
    const int wgid = (orig & 7) * (nwg >> 3) + (orig >> 3);
    const int s = wgid >> 6, q = wgid & 63;
    const int nsx = gx >> 3;
    const int sy = s / nsx, sx = s - sy * nsx;
    by = sy * 8 + (q >> 3);
    bx = sx * 8 + (q & 7);
}

// ---------------- gemm_s: SINGLE-buffered m97-style loop (replay-proven) ----
// stage-DMA -> vmcnt(0)+barrier -> compute -> barrier.
template<int BM, int BN, int FM, int FN, int WM, int WN, int OCC>
__global__ __launch_bounds__(256, OCC) void gemm_s(
    const u16* __restrict__ A, const u16* __restrict__ Bt,
    const float* __restrict__ bias, const float* resid,
    float* Cf, u16* Cb, int M, int N, int Kst, int Kl, int do_gelu) {
    __shared__ u16 sA[BM][64];
    __shared__ u16 sB[BN][64];
    constexpr int NA = BM / 32;
    constexpr int NB = BN / 32;
    const int tid = threadIdx.x;
    const int lane = tid & 63, w = tid >> 6;
    const int lr = lane & 15, g = lane >> 4;
    const int wm = w / WN, wn = w % WN;

    A  += (size_t)blockIdx.z * Kl;
    Bt += (size_t)blockIdx.z * Kl;
    Cf += (size_t)blockIdx.z * M * N;

    int bx, by;
    xcd_map(bx, by);
    const long m0 = (long)by * BM, n0 = (long)bx * BN;

    const f32x4 fzero = {0.f, 0.f, 0.f, 0.f};
    f32x4 acc[FM][FN];
#pragma unroll
    for (int i = 0; i < FM; ++i)
#pragma unroll
        for (int j = 0; j < FN; ++j) acc[i][j] = fzero;

    const int nt = Kl / 64;
    const int srow = lane >> 3, scc = lane & 7;
    const u16* pa[NA];
    const u16* pb[NB];
#pragma unroll
    for (int r = 0; r < NA; ++r)
        pa[r] = A + (size_t)(m0 + r * 32 + w * 8 + srow) * Kst + ((scc ^ srow) * 8);
#pragma unroll
    for (int r = 0; r < NB; ++r)
        pb[r] = Bt + (size_t)(n0 + r * 32 + w * 8 + srow) * Kst + ((scc ^ srow) * 8);

    for (int t = 0; t < nt; ++t) {
#pragma unroll
        for (int r = 0; r < NA; ++r) { gload16(pa[r], &sA[r * 32 + w * 8][0]); pa[r] += 64; }
#pragma unroll
        for (int r = 0; r < NB; ++r) { gload16(pb[r], &sB[r * 32 + w * 8][0]); pb[r] += 64; }
        asm volatile("s_waitcnt vmcnt(0)" ::: "memory");
        __builtin_amdgcn_sched_barrier(0);
        __syncthreads();
#pragma unroll
        for (int ks = 0; ks < 2; ++ks) {
            bf16x8 fa[FM], fb[FN];
#pragma unroll
            for (int mi = 0; mi < FM; ++mi) {
                int row = wm * (16 * FM) + mi * 16 + lr;
                fa[mi] = *(const bf16x8*)&sA[row][((ks * 4 + g) ^ (row & 7)) * 8];
            }
#pragma unroll
            for (int ni = 0; ni < FN; ++ni) {
                int row = wn * (16 * FN) + ni * 16 + lr;
                fb[ni] = *(const bf16x8*)&sB[row][((ks * 4 + g) ^ (row & 7)) * 8];
            }
#pragma unroll
            for (int mi = 0; mi < FM; ++mi)
#pragma unroll
                for (int ni = 0; ni < FN; ++ni)
                    acc[mi][ni] = __builtin_amdgcn_mfma_f32_16x16x32_bf16(
                        fa[mi], fb[ni], acc[mi][ni], 0, 0, 0);
        }
        __syncthreads();
    }
#pragma unroll
    for (int mi = 0; mi < FM; ++mi) {
#pragma unroll
        for (int ni = 0; ni < FN; ++ni) {
            const long nc = n0 + wn * (16 * FN) + ni * 16 + lr;
            const float bvv = bias ? bias[nc] : 0.0f;
#pragma unroll
            for (int j = 0; j < 4; ++j) {
                const long mr = m0 + wm * (16 * FM) + mi * 16 + g * 4 + j;
                float v = acc[mi][ni][j] + bvv;
                if (resid) v += resid[(size_t)mr * N + nc];
                if (do_gelu) v = gelu_f(v);
                if (Cf) Cf[(size_t)mr * N + nc] = v;
                if (Cb) Cb[(size_t)mr * N + nc] = f2b(v);
            }
        }
    }
}

// ---------------- causal flash attention -----------------------------------
// K/V double-buffered in LDS with register prefetch (1 barrier/iter);
// long-first qc order (reversed) hides causal-triangle tail.
__global__ __launch_bounds__(256, 2) void attn_kernel(
    const u16* __restrict__ qkv, const u16* __restrict__ Vt, u16* __restrict__ Yg) {
    __shared__ u16 sK[2][64][64];
    __shared__ u16 sV[2][64][64];
    __shared__ u16 sP[4][16][64];
    const int tid = threadIdx.x, w = tid >> 6, lane = tid & 63;
    const int lr = lane & 15, g = lane >> 4;
    const int hw = blockIdx.x;
    const int xcd = hw & 7, slot = hw >> 3;        // slot 0..63
    const int bh = xcd + 8 * (slot >> 4);          // 0..31
    const int qc = 15 - (slot & 15);               // 64-row chunk, LONG FIRST
    const int h = bh & 15, b = bh >> 4;
    const int tq0 = qc * 64 + w * 16;
    const u16* Qp = qkv + (size_t)b * Tc * Sq + h * 64;
    const u16* Kp = qkv + (size_t)b * Tc * Sq + Dc + h * 64;
    const u16* Vp = Vt + ((size_t)b * Dc + h * 64) * Tc;

    bf16x8 qf[2];
#pragma unroll
    for (int ks = 0; ks < 2; ++ks)
        qf[ks] = *(const bf16x8*)(Qp + (size_t)(tq0 + lr) * Sq + ks * 32 + g * 8);

    const f32x4 fzero = {0.f, 0.f, 0.f, 0.f};
    f32x4 o[4];
    float mst[4], lst[4];
#pragma unroll
    for (int j = 0; j < 4; ++j) { mst[j] = -1e30f; lst[j] = 0.f; }
#pragma unroll
    for (int ni = 0; ni < 4; ++ni) o[ni] = fzero;

    const int c0 = tid, c1 = tid + 256;
    const int row0 = c0 >> 3, cc0 = c0 & 7;
    const int row1 = c1 >> 3, cc1 = c1 & 7;
    bf16x8 kr[2], vr[2];
    auto kvload = [&](int jk) {
        kr[0] = *(const bf16x8*)(Kp + (size_t)(jk * 64 + row0) * Sq + cc0 * 8);
        kr[1] = *(const bf16x8*)(Kp + (size_t)(jk * 64 + row1) * Sq + cc1 * 8);
        vr[0] = *(const bf16x8*)(Vp + (size_t)row0 * Tc + jk * 64 + cc0 * 8);
        vr[1] = *(const bf16x8*)(Vp + (size_t)row1 * Tc + jk * 64 + cc1 * 8);
    };
    auto kvwrite = [&](int buf) {
        *(bf16x8*)&sK[buf][row0][(cc0 ^ (row0 & 7)) * 8] = kr[0];
        *(bf16x8*)&sK[buf][row1][(cc1 ^ (row1 & 7)) * 8] = kr[1];
        *(bf16x8*)&sV[buf][row0][(cc0 ^ (row0 & 7)) * 8] = vr[0];
        *(bf16x8*)&sV[buf][row1][(cc1 ^ (row1 & 7)) * 8] = vr[1];
    };

    kvload(0);
    kvwrite(0);
    __syncthreads();
    for (int jk = 0; jk <= qc; ++jk) {
        const int cur = jk & 1;
        if (jk < qc) kvload(jk + 1);
        // QK^T
        f32x4 s[4];
#pragma unroll
        for (int ni = 0; ni < 4; ++ni) {
            const int row = ni * 16 + lr;
            bf16x8 kf0 = *(const bf16x8*)&sK[cur][row][((0 + g) ^ (lr & 7)) * 8];
            bf16x8 kf1 = *(const bf16x8*)&sK[cur][row][((4 + g) ^ (lr & 7)) * 8];
            s[ni] = __builtin_amdgcn_mfma_f32_16x16x32_bf16(qf[0], kf0, fzero, 0, 0, 0);
            s[ni] = __builtin_amdgcn_mfma_f32_16x16x32_bf16(qf[1], kf1, s[ni], 0, 0, 0);
        }
#pragma unroll
        for (int ni = 0; ni < 4; ++ni)
#pragma unroll
            for (int j = 0; j < 4; ++j) {
                float v = s[ni][j] * 0.125f;
                int tk = jk * 64 + ni * 16 + lr;
                int tq = tq0 + g * 4 + j;
                if (tk > tq) v = -1e30f;
                s[ni][j] = v;
            }
        float fs[4];
#pragma unroll
        for (int j = 0; j < 4; ++j) {
            float pm = fmaxf(fmaxf(s[0][j], s[1][j]), fmaxf(s[2][j], s[3][j]));
            pm = fmaxf(pm, __shfl_xor(pm, 1, 16));
            pm = fmaxf(pm, __shfl_xor(pm, 2, 16));
            pm = fmaxf(pm, __shfl_xor(pm, 4, 16));
            pm = fmaxf(pm, __shfl_xor(pm, 8, 16));
            const float m2 = fmaxf(mst[j], pm);
            fs[j] = __expf(mst[j] - m2);
#pragma unroll
            for (int ni = 0; ni < 4; ++ni)
                s[ni][j] = __expf(s[ni][j] - m2);
            float rsum = s[0][j] + s[1][j] + s[2][j] + s[3][j];
            rsum += __shfl_xor(rsum, 1, 16);
            rsum += __shfl_xor(rsum, 2, 16);
            rsum += __shfl_xor(rsum, 4, 16);
            rsum += __shfl_xor(rsum, 8, 16);
            lst[j] = lst[j] * fs[j] + rsum;
            mst[j] = m2;
        }
#pragma unroll
        for (int ni = 0; ni < 4; ++ni)
#pragma unroll
            for (int j = 0; j < 4; ++j) o[ni][j] *= fs[j];
#pragma unroll
        for (int ni = 0; ni < 4; ++ni)
#pragma unroll
            for (int j = 0; j < 4; ++j) {
                int row = g * 4 + j;
                int col = ni * 16 + lr;
                sP[w][row][(((col >> 3) ^ (row & 7)) << 3) | (col & 7)] = f2b(s[ni][j]);
            }
#pragma unroll
        for (int ks = 0; ks < 2; ++ks) {
            bf16x8 pf = *(const bf16x8*)&sP[w][lr][((ks * 4 + g) ^ (lr & 7)) * 8];
#pragma unroll
            for (int ni = 0; ni < 4; ++ni) {
                const int row = ni * 16 + lr;
                bf16x8 vf = *(const bf16x8*)&sV[cur][row][((ks * 4 + g) ^ (lr & 7)) * 8];
                o[ni] = __builtin_amdgcn_mfma_f32_16x16x32_bf16(pf, vf, o[ni], 0, 0, 0);
            }
        }
        if (jk < qc) kvwrite(cur ^ 1);
        __syncthreads();
    }
#pragma unroll
    for (int ni = 0; ni < 4; ++ni)
#pragma unroll
        for (int j = 0; j < 4; ++j) {
            int tq = tq0 + g * 4 + j;
            int col = h * 64 + ni * 16 + lr;
            Yg[(size_t)(b * Tc + tq) * Dc + col] = f2b(o[ni][j] / lst[j]);
        }
}

// ---------------------------------------------------------------------------
extern "C" void kernel_launch(void* const* d_in, const int* in_sizes, int n_in,
                              void* d_out, int out_size, void* d_ws, size_t ws_size,
                              hipStream_t stream) {
    const float* obs    = (const float*)d_in[0];
    const float* enc_w1 = (const float*)d_in[1];
    const float* enc_b1 = (const float*)d_in[2];
    const float* enc_g1 = (const float*)d_in[3];
    const float* enc_be1= (const float*)d_in[4];
    const float* enc_w2 = (const float*)d_in[5];
    const float* enc_b2 = (const float*)d_in[6];
    const float* enc_w3 = (const float*)d_in[7];
    const float* enc_b3 = (const float*)d_in[8];
    const float* enc_g2 = (const float*)d_in[9];
    const float* enc_be2= (const float*)d_in[10];
    const float* pos_emb= (const float*)d_in[11];
    const float* ln1_g  = (const float*)d_in[12];
    const float* ln1_b  = (const float*)d_in[13];
    const float* wq     = (const float*)d_in[14];
    const float* bq     = (const float*)d_in[15];
    const float* wk     = (const float*)d_in[16];
    const float* bk     = (const float*)d_in[17];
    const float* wv     = (const float*)d_in[18];
    const float* bv     = (const float*)d_in[19];
    const float* wo     = (const float*)d_in[20];
    const float* bo     = (const float*)d_in[21];
    const float* ln2_g  = (const float*)d_in[22];
    const float* ln2_b  = (const float*)d_in[23];
    const float* mlp_w1 = (const float*)d_in[24];
    const float* mlp_b1 = (const float*)d_in[25];
    const float* mlp_w2 = (const float*)d_in[26];
    const float* mlp_b2 = (const float*)d_in[27];
    const float* lnf_g  = (const float*)d_in[28];
    const float* lnf_b  = (const float*)d_in[29];
    const float* dec_w  = (const float*)d_in[30];
    const float* dec_b  = (const float*)d_in[31];

    float* out_x = (float*)d_out;
    float* out_o = out_x + (size_t)Mc * Dc;

    char* base = (char*)d_ws;
    size_t off = 0;
    auto ab = [&](size_t e) -> u16* {
        u16* r = (u16*)(base + off); off += (e * 2 + 255) & ~(size_t)255; return r; };
    auto af = [&](size_t e) -> float* {
        float* r = (float*)(base + off); off += (e * 4 + 255) & ~(size_t)255; return r; };

    u16* wt_e1   = ab((size_t)Dc * Oc);
    u16* wt_e2   = ab((size_t)Dc * Dc);
    u16* wt_e3   = ab((size_t)Dc * Dc);
    u16* wtqkv   = ab((size_t)Lc * 3 * Dc * Dc);
    u16* wto     = ab((size_t)Lc * Dc * Dc);
    u16* wtm1    = ab((size_t)Lc * Dc * FFc);
    u16* wtm2    = ab((size_t)Lc * FFc * Dc);
    u16* wt_d    = ab((size_t)Oc * Dc);
    float* qkvb  = af((size_t)Lc * Sq);

    u16*   obs_bf = ab((size_t)Mc * Oc);
    float* tmpf   = af((size_t)Mc * Dc);
    float* xf     = af((size_t)Mc * Dc);
    float* x2f    = af((size_t)Mc * Dc);
    u16*   hn_bf  = ab((size_t)Mc * Dc);
    u16*   qkv    = ab((size_t)Mc * Sq);
    u16*   vT     = ab((size_t)Mc * Dc);
    u16*   y_bf   = ab((size_t)Mc * Dc);
    u16*   ff_bf  = ab((size_t)Mc * FFc);
    float* pk     = af((size_t)4 * Mc * Dc);   // split-K partials (4 planes)

    // ---- uber weight prep: ONE launch for all transposes (64x64, nt-read) ----
    WTTab tab;
    long cum = 0;
    auto seg = [&](int i, const float* src, u16* dst, int R, int C, int nz,
                   long inB, long outB) {
        int tpz = (R / 64) * (C / 64);
        cum += (long)tpz * nz;
        tab.e[i] = WTSeg{src, dst, R, C, tpz, inB, outB, cum};
    };
    seg(0, enc_w1, wt_e1, Oc, Dc, 1, 0, 0);
    seg(1, enc_w2, wt_e2, Dc, Dc, 1, 0, 0);
    seg(2, enc_w3, wt_e3, Dc, Dc, 1, 0, 0);
    seg(3, wq, wtqkv,              Dc, Dc, Lc, (long)Dc * Dc, (long)3 * Dc * Dc);
    seg(4, wk, wtqkv + Dc * Dc,    Dc, Dc, Lc, (long)Dc * Dc, (long)3 * Dc * Dc);
    seg(5, wv, wtqkv + 2 * Dc * Dc,Dc, Dc, Lc, (long)Dc * Dc, (long)3 * Dc * Dc);
    seg(6, wo, wto, Dc, Dc, Lc, (long)Dc * Dc, (long)Dc * Dc);
    seg(7, mlp_w1, wtm1, Dc, FFc, Lc, (long)Dc * FFc, (long)Dc * FFc);
    seg(8, mlp_w2, wtm2, FFc, Dc, Lc, (long)Dc * FFc, (long)Dc * FFc);
    seg(9, dec_w, wt_d, Dc, Oc, 1, 0, 0);
    uber_wtrans<<<dim3((unsigned)cum), 256, 0, stream>>>(tab);
    pack_qkv_bias<<<dim3(Lc * Sq / 256), 256, 0, stream>>>(bq, bk, bv, qkvb);
    cvt_bf<<<dim3((Mc * Oc / 4 + 255) / 256), 256, 0, stream>>>(obs, obs_bf, Mc * Oc);

    // big-N GEMMs: 128x64 tile, 4 blocks/CU;  small GEMMs: 64x64 tile
    auto gS = [&](const u16* A, const u16* Bt, const float* bias, const float* resid,
                  float* Cf, u16* Cb, int M, int N, int K, int gel) {
        gemm_s<128, 64, 4, 2, 2, 2, 4><<<dim3(N / 64, M / 128), 256, 0, stream>>>(
            A, Bt, bias, resid, Cf, Cb, M, N, K, K, gel);
    };
    auto g64 = [&](const u16* A, const u16* Bt, const float* bias, const float* resid,
                   float* Cf, u16* Cb, int M, int N, int K, int gel) {
        gemm_s<64, 64, 2, 2, 2, 2, 4><<<dim3(N / 64, M / 64), 256, 0, stream>>>(
            A, Bt, bias, resid, Cf, Cb, M, N, K, K, gel);
    };
    auto lnk = [&](const float* in, const float* gg, const float* bb, const float* pos,
                   float* outf, u16* outb, int gel) {
        ln_kernel<<<dim3(Mc), 256, 0, stream>>>(in, gg, bb, pos, outf, outb, gel);
    };

    // encoder MLP
    g64(obs_bf, wt_e1, enc_b1, nullptr, tmpf, nullptr, Mc, Dc, Oc, 0);
    lnk(tmpf, enc_g1, enc_be1, nullptr, nullptr, hn_bf, 1);
    g64(hn_bf, wt_e2, enc_b2, nullptr, nullptr, y_bf, Mc, Dc, Dc, 1);
    g64(y_bf, wt_e3, enc_b3, nullptr, tmpf, nullptr, Mc, Dc, Dc, 0);
    lnk(tmpf, enc_g2, enc_be2, pos_emb, xf, nullptr, 0);

    // ln1 of layer 0
    lnk(xf, ln1_g, ln1_b, nullptr, nullptr, hn_bf, 0);

    // transformer blocks
    for (int l = 0; l < Lc; ++l) {
        gS(hn_bf, wtqkv + (size_t)l * 3 * Dc * Dc, qkvb + (size_t)l * Sq, nullptr,
           nullptr, qkv, Mc, Sq, Dc, 0);
        btrans<<<dim3(Dc / 32, Tc / 32, Bc), 256, 0, stream>>>(qkv + 2 * Dc, vT, Sq);
        attn_kernel<<<dim3(Bc * Hc * (Tc / 64)), 256, 0, stream>>>(qkv, vT, y_bf);
        // wo projection: split-K=2 -> fp32 partials, 1024 blocks (4/CU)
        gemm_s<64, 64, 2, 2, 2, 2, 4><<<dim3(Dc / 64, Mc / 64, 2), 256, 0, stream>>>(
            y_bf, wto + (size_t)l * Dc * Dc, nullptr, nullptr, pk, nullptr,
            Mc, Dc, Dc, Dc / 2, 0);
        // fused: x2f = p0+p1+bo+xf ; ln2 -> hn_bf
        red2_ln<2><<<dim3(Mc), 256, 0, stream>>>(
            pk, bo + (size_t)l * Dc, xf, x2f,
            ln2_g + (size_t)l * Dc, ln2_b + (size_t)l * Dc, nullptr, hn_bf);
        gS(hn_bf, wtm1 + (size_t)l * Dc * FFc, mlp_b1 + (size_t)l * FFc, nullptr,
           nullptr, ff_bf, Mc, FFc, Dc, 1);
        // mlp2: split-K=4 -> fp32 partials (128x64 tile, 1024 blocks -> 4/CU)
        gemm_s<128, 64, 4, 2, 2, 2, 4><<<dim3(Dc / 64, Mc / 128, 4), 256, 0, stream>>>(
            ff_bf, wtm2 + (size_t)l * FFc * Dc, nullptr, nullptr, pk, nullptr,
            Mc, Dc, FFc, FFc / 4, 0);
        // fused reduce(+bias+resid) -> xf, then LN (ln1[l+1] or lnf)
        if (l < Lc - 1) {
            red2_ln<4><<<dim3(Mc), 256, 0, stream>>>(
                pk, mlp_b2 + (size_t)l * Dc, x2f, xf,
                ln1_g + (size_t)(l + 1) * Dc, ln1_b + (size_t)(l + 1) * Dc,
                nullptr, hn_bf);
        } else {
            red2_ln<4><<<dim3(Mc), 256, 0, stream>>>(
                pk, mlp_b2 + (size_t)l * Dc, x2f, xf,
                lnf_g, lnf_b, out_x, hn_bf);
        }
    }

    // decoder
    g64(hn_bf, wt_d, dec_b, nullptr, out_o, nullptr, Mc, Oc, Dc, 0);
}